// Round 6
// baseline (312.326 us; speedup 1.0000x reference)
//
#include <hip/hip_runtime.h>
#include <hip/hip_bf16.h>
#include <cstdint>
#include <cstddef>

typedef __bf16 bf16;
typedef __bf16 bf16x4 __attribute__((ext_vector_type(4)));
typedef __bf16 bf16x8 __attribute__((ext_vector_type(8)));
typedef float f32x4 __attribute__((ext_vector_type(4)));

#define NB 4
#define NS 2048
#define ND 1024
#define NH 16
#define NHD 64
#define NM (NB * NS)  // 8192

// async global->LDS, 16B per lane; LDS dest = wave-uniform base + lane*16
__device__ inline void lds_dma16(const bf16* g, bf16* l) {
    __builtin_amdgcn_global_load_lds(
        (const __attribute__((address_space(1))) void*)g,
        (__attribute__((address_space(3))) void*)l, 16, 0, 0);
}

// ---------------------------------------------------------------------------
// RoPE cos/sin table: [s][f], f in [0,32), angle = s * 10000^(-f/32), fp32.
// ---------------------------------------------------------------------------
__global__ void rope_table_kernel(float* __restrict__ cost, float* __restrict__ sint) {
    int i = blockIdx.x * 256 + threadIdx.x;  // 0..65535
    int s = i >> 5, f = i & 31;
    float inv = exp2f(-(float)f * (13.287712379549449f / 32.0f));
    float ang = (float)s * inv;
    cost[i] = cosf(ang);
    sint[i] = sinf(ang);
}

// fp32 -> bf16 bulk convert (float4 per thread)
__global__ void cvt_bf16_kernel(const float4* __restrict__ in, bf16x4* __restrict__ out) {
    int i = blockIdx.x * 256 + threadIdx.x;
    float4 v = in[i];
    bf16x4 r = {(bf16)v.x, (bf16)v.y, (bf16)v.z, (bf16)v.w};
    out[i] = r;
}

// ---------------------------------------------------------------------------
// QKV GEMM: m97 structure + double-buffered dma (dma for tile i+1 issued at
// iter start -> full compute-phase in flight before the barrier drain).
// C[m][n] = sum_k A[m][k]*W[n][k] + bias[n], fused RoPE epilogue.
// ---------------------------------------------------------------------------
__global__ void __launch_bounds__(256) qkv_rope_gemm(
    const bf16* __restrict__ A, const bf16* __restrict__ W,
    const float* __restrict__ bias,
    const float* __restrict__ cost, const float* __restrict__ sint,
    bf16* __restrict__ Qw, bf16* __restrict__ Kw, bf16* __restrict__ Vt) {
    __shared__ __attribute__((aligned(16))) bf16 lA[2][128 * 32];
    __shared__ __attribute__((aligned(16))) bf16 lB[2][128 * 32];

    int t = threadIdx.x, lane = t & 63, w = t >> 6;
    int col = lane & 15, quad = lane >> 4;
    int m0 = blockIdx.y * 128, n0 = blockIdx.x * 128;
    int wm = (w >> 1) * 64, wn = (w & 1) * 64;

    f32x4 acc[4][4];
#pragma unroll
    for (int i = 0; i < 4; ++i)
#pragma unroll
        for (int j = 0; j < 4; ++j) acc[i][j] = (f32x4){0.f, 0.f, 0.f, 0.f};

    const bf16* gA0 = A + (size_t)(m0 + w * 32 + (lane >> 2)) * ND + (lane & 3) * 8;
    const bf16* gA1 = gA0 + (size_t)16 * ND;
    const bf16* gB0 = W + (size_t)(n0 + w * 32 + (lane >> 2)) * ND + (lane & 3) * 8;
    const bf16* gB1 = gB0 + (size_t)16 * ND;
    int ldsOff0 = (w * 32) * 32;
    int ldsOff1 = (w * 32 + 16) * 32;

    // prologue: tile 0 into buf 0
    lds_dma16(gA0, &lA[0][ldsOff0]);
    lds_dma16(gA1, &lA[0][ldsOff1]);
    lds_dma16(gB0, &lB[0][ldsOff0]);
    lds_dma16(gB1, &lB[0][ldsOff1]);
    __syncthreads();

    for (int i = 0; i < 32; ++i) {
        int cur = i & 1, nxt = cur ^ 1;
        if (i + 1 < 32) {  // dma next tile now; drains at the barrier below,
                           // after a full compute phase in flight
            int kt = (i + 1) * 32;
            lds_dma16(gA0 + kt, &lA[nxt][ldsOff0]);
            lds_dma16(gA1 + kt, &lA[nxt][ldsOff1]);
            lds_dma16(gB0 + kt, &lB[nxt][ldsOff0]);
            lds_dma16(gB1 + kt, &lB[nxt][ldsOff1]);
        }
        bf16x8 af[4], bg[4];
#pragma unroll
        for (int ii = 0; ii < 4; ++ii)
            af[ii] = *(const bf16x8*)&lA[cur][(wm + ii * 16 + col) * 32 + quad * 8];
#pragma unroll
        for (int j = 0; j < 4; ++j)
            bg[j] = *(const bf16x8*)&lB[cur][(wn + j * 16 + col) * 32 + quad * 8];
#pragma unroll
        for (int ii = 0; ii < 4; ++ii)
#pragma unroll
            for (int j = 0; j < 4; ++j)
                acc[ii][j] = __builtin_amdgcn_mfma_f32_16x16x32_bf16(af[ii], bg[j], acc[ii][j], 0, 0, 0);
        __syncthreads();
    }

    // Epilogue (verified r2-r5). Wave's 64 n-cols lie in one (which, head) seg.
    int nseg = n0 + wn;
    int which = nseg >> 10;
    int h = (nseg >> 6) & (NH - 1);
    float bj[4];
#pragma unroll
    for (int j = 0; j < 4; ++j) bj[j] = bias[nseg + j * 16 + col];

#pragma unroll
    for (int i = 0; i < 4; ++i) {
#pragma unroll
        for (int r = 0; r < 4; ++r) {
            int m = m0 + wm + i * 16 + quad * 4 + r;
            int b = m >> 11, s = m & (NS - 1);
            float v0 = acc[i][0][r] + bj[0];
            float v1 = acc[i][1][r] + bj[1];
            float v2 = acc[i][2][r] + bj[2];
            float v3 = acc[i][3][r] + bj[3];
            if (which == 2) {
                bf16* dst = Vt + (size_t)(b * NH + h) * NHD * NS;
                dst[(size_t)(col) * NS + s] = (bf16)v0;
                dst[(size_t)(16 + col) * NS + s] = (bf16)v1;
                dst[(size_t)(32 + col) * NS + s] = (bf16)v2;
                dst[(size_t)(48 + col) * NS + s] = (bf16)v3;
            } else {
                bf16* dst = (which ? Kw : Qw) + ((size_t)(b * NH + h) * NS + s) * NHD;
                float c0 = cost[s * 32 + col], s0 = sint[s * 32 + col];
                float c1 = cost[s * 32 + 16 + col], s1 = sint[s * 32 + 16 + col];
                dst[col] = (bf16)(v0 * c0 - v2 * s0);
                dst[16 + col] = (bf16)(v1 * c1 - v3 * s1);
                dst[32 + col] = (bf16)(v0 * s0 + v2 * c0);
                dst[48 + col] = (bf16)(v1 * s1 + v3 * c1);
            }
        }
    }
}

// ---------------------------------------------------------------------------
// Flash attention v6: 64 q-rows per wave (4 m-blocks, 256 q/block), 32-key
// tiles, double-buffered LDS with ONE barrier per tile. Gloads for tile i+2
// issued right after the barrier (full compute phase in flight); ds_write of
// tile i+1 at iter end. In-lane P-fragment + fixed-max softmax as r4/r5.
// ---------------------------------------------------------------------------
__global__ void __launch_bounds__(256, 2) attn_kernel(
    const bf16* __restrict__ Qw, const bf16* __restrict__ Kw,
    const bf16* __restrict__ Vt, bf16* __restrict__ X) {
    const int LDK = 72;
    const int LV = 40;
    __shared__ __attribute__((aligned(16))) bf16 lK[2][32 * LDK];  // 9.2 KB
    __shared__ __attribute__((aligned(16))) bf16 lV[2][64 * LV];   // 10.2 KB

    int t = threadIdx.x, lane = t & 63, w = t >> 6;
    int col = lane & 15, q = lane >> 4;
    int bh = blockIdx.y, b = bh >> 4, h = bh & 15;
    int q0 = blockIdx.x * 256 + w * 64;   // 64 q-rows per wave
    const bf16* Qh = Qw + (size_t)bh * NS * NHD;
    const bf16* Kh = Kw + (size_t)bh * NS * NHD;
    const bf16* Vh = Vt + (size_t)bh * NHD * NS;

    int krow = t >> 3, kc = t & 7;
    int vrow = t >> 2, vc = t & 3;
    const bf16* gK = Kh + (size_t)krow * NHD + kc * 8;
    const bf16* gV = Vh + (size_t)vrow * NS + vc * 8;
    int wKoff = krow * LDK + kc * 8;
    int wVoff = vrow * LV + vc * 8;

    // Q b-frags: B[n=q-row][k=hd], lane: n=col, k=q*8+j (+32)
    bf16x8 bQ[4][2];
#pragma unroll
    for (int mb = 0; mb < 4; ++mb)
#pragma unroll
        for (int h2 = 0; h2 < 2; ++h2)
            bQ[mb][h2] = *(const bf16x8*)(Qh + (size_t)(q0 + mb * 16 + col) * NHD + h2 * 32 + q * 8);

    f32x4 o[4][4];
#pragma unroll
    for (int mb = 0; mb < 4; ++mb)
#pragma unroll
        for (int hb = 0; hb < 4; ++hb) o[mb][hb] = (f32x4){0.f, 0.f, 0.f, 0.f};
    float dsum[4] = {0.f, 0.f, 0.f, 0.f};

    // pipeline prologue: tiles 0,1 -> reg sets 0,1; tile 0 -> LDS buf 0
    bf16x8 kr[2], vr[2];
    kr[0] = *(const bf16x8*)gK;
    vr[0] = *(const bf16x8*)gV;
    kr[1] = *(const bf16x8*)(gK + (size_t)32 * NHD);
    vr[1] = *(const bf16x8*)(gV + 32);
    *(bf16x8*)&lK[0][wKoff] = kr[0];
    *(bf16x8*)&lV[0][wVoff] = vr[0];

#pragma unroll 2
    for (int it = 0; it < 64; ++it) {
        __syncthreads();  // buf[it&1] visible; buf[(it+1)&1] readers (it-1) done
        int cur = it & 1, nxt = cur ^ 1;
        if (it + 2 < 64) {  // tile it+2 -> reg set cur (freed by write at it-1)
            kr[cur] = *(const bf16x8*)(gK + (size_t)(it + 2) * 32 * NHD);
            vr[cur] = *(const bf16x8*)(gV + (it + 2) * 32);
        }

        bf16x8 aK[2][2];
#pragma unroll
        for (int tb = 0; tb < 2; ++tb)
#pragma unroll
            for (int h2 = 0; h2 < 2; ++h2)
                aK[tb][h2] = *(const bf16x8*)&lK[cur][(tb * 16 + col) * LDK + h2 * 32 + q * 8];
        bf16x8 vf[4];
#pragma unroll
        for (int hb = 0; hb < 4; ++hb) {
            const bf16* vp = &lV[cur][(hb * 16 + col) * LV + q * 4];
            bf16x4 lo = *(const bf16x4*)vp;
            bf16x4 hi = *(const bf16x4*)(vp + 16);
            vf[hb] = __builtin_shufflevector(lo, hi, 0, 1, 2, 3, 4, 5, 6, 7);
        }
#pragma unroll
        for (int mb = 0; mb < 4; ++mb) {
            f32x4 s0 = (f32x4){0.f, 0.f, 0.f, 0.f};
            f32x4 s1 = (f32x4){0.f, 0.f, 0.f, 0.f};
            s0 = __builtin_amdgcn_mfma_f32_16x16x32_bf16(aK[0][0], bQ[mb][0], s0, 0, 0, 0);
            s0 = __builtin_amdgcn_mfma_f32_16x16x32_bf16(aK[0][1], bQ[mb][1], s0, 0, 0, 0);
            s1 = __builtin_amdgcn_mfma_f32_16x16x32_bf16(aK[1][0], bQ[mb][0], s1, 0, 0, 0);
            s1 = __builtin_amdgcn_mfma_f32_16x16x32_bf16(aK[1][1], bQ[mb][1], s1, 0, 0, 0);
            bf16x8 pf;
            float ds = 0.f;
#pragma unroll
            for (int r = 0; r < 4; ++r) {
                float p0 = __expf(s0[r] * 0.125f);
                float p1 = __expf(s1[r] * 0.125f);
                pf[r] = (bf16)p0;
                pf[4 + r] = (bf16)p1;
                ds += p0 + p1;
            }
            dsum[mb] += ds;
#pragma unroll
            for (int hb = 0; hb < 4; ++hb)
                o[mb][hb] = __builtin_amdgcn_mfma_f32_16x16x32_bf16(vf[hb], pf, o[mb][hb], 0, 0, 0);
        }

        if (it + 1 < 64) {  // stage tile it+1 (reg set nxt) into buf nxt
            *(bf16x8*)&lK[nxt][wKoff] = kr[nxt];
            *(bf16x8*)&lV[nxt][wVoff] = vr[nxt];
        }
    }

#pragma unroll
    for (int mb = 0; mb < 4; ++mb) {
        dsum[mb] += __shfl_xor(dsum[mb], 16);
        dsum[mb] += __shfl_xor(dsum[mb], 32);
        float linv = 1.0f / dsum[mb];
        int s = q0 + mb * 16 + col;
        bf16* dst = X + (size_t)(b * NS + s) * ND + h * NHD;
#pragma unroll
        for (int hb = 0; hb < 4; ++hb) {
            bf16x4 ov = {(bf16)(o[mb][hb][0] * linv), (bf16)(o[mb][hb][1] * linv),
                         (bf16)(o[mb][hb][2] * linv), (bf16)(o[mb][hb][3] * linv)};
            *(bf16x4*)(dst + hb * 16 + q * 4) = ov;
        }
    }
}

// ---------------------------------------------------------------------------
// Output projection: same dbuf-dma structure. out fp32.
// ---------------------------------------------------------------------------
__global__ void __launch_bounds__(256) out_gemm(
    const bf16* __restrict__ A, const bf16* __restrict__ W,
    const float* __restrict__ bias, float* __restrict__ out) {
    __shared__ __attribute__((aligned(16))) bf16 lA[2][128 * 32];
    __shared__ __attribute__((aligned(16))) bf16 lB[2][128 * 32];

    int t = threadIdx.x, lane = t & 63, w = t >> 6;
    int col = lane & 15, quad = lane >> 4;
    int m0 = blockIdx.y * 128, n0 = blockIdx.x * 128;
    int wm = (w >> 1) * 64, wn = (w & 1) * 64;

    f32x4 acc[4][4];
#pragma unroll
    for (int i = 0; i < 4; ++i)
#pragma unroll
        for (int j = 0; j < 4; ++j) acc[i][j] = (f32x4){0.f, 0.f, 0.f, 0.f};

    const bf16* gA0 = A + (size_t)(m0 + w * 32 + (lane >> 2)) * ND + (lane & 3) * 8;
    const bf16* gA1 = gA0 + (size_t)16 * ND;
    const bf16* gB0 = W + (size_t)(n0 + w * 32 + (lane >> 2)) * ND + (lane & 3) * 8;
    const bf16* gB1 = gB0 + (size_t)16 * ND;
    int ldsOff0 = (w * 32) * 32;
    int ldsOff1 = (w * 32 + 16) * 32;

    lds_dma16(gA0, &lA[0][ldsOff0]);
    lds_dma16(gA1, &lA[0][ldsOff1]);
    lds_dma16(gB0, &lB[0][ldsOff0]);
    lds_dma16(gB1, &lB[0][ldsOff1]);
    __syncthreads();

    for (int i = 0; i < 32; ++i) {
        int cur = i & 1, nxt = cur ^ 1;
        if (i + 1 < 32) {
            int kt = (i + 1) * 32;
            lds_dma16(gA0 + kt, &lA[nxt][ldsOff0]);
            lds_dma16(gA1 + kt, &lA[nxt][ldsOff1]);
            lds_dma16(gB0 + kt, &lB[nxt][ldsOff0]);
            lds_dma16(gB1 + kt, &lB[nxt][ldsOff1]);
        }
        bf16x8 af[4], bg[4];
#pragma unroll
        for (int ii = 0; ii < 4; ++ii)
            af[ii] = *(const bf16x8*)&lA[cur][(wm + ii * 16 + col) * 32 + quad * 8];
#pragma unroll
        for (int j = 0; j < 4; ++j)
            bg[j] = *(const bf16x8*)&lB[cur][(wn + j * 16 + col) * 32 + quad * 8];
#pragma unroll
        for (int ii = 0; ii < 4; ++ii)
#pragma unroll
            for (int j = 0; j < 4; ++j)
                acc[ii][j] = __builtin_amdgcn_mfma_f32_16x16x32_bf16(af[ii], bg[j], acc[ii][j], 0, 0, 0);
        __syncthreads();
    }

    float bj[4];
#pragma unroll
    for (int j = 0; j < 4; ++j) bj[j] = bias[n0 + wn + j * 16 + col];
#pragma unroll
    for (int i = 0; i < 4; ++i)
#pragma unroll
        for (int r = 0; r < 4; ++r) {
            int m = m0 + wm + i * 16 + quad * 4 + r;
#pragma unroll
            for (int j = 0; j < 4; ++j)
                out[(size_t)m * ND + n0 + wn + j * 16 + col] = acc[i][j][r] + bj[j];
        }
}

// ---------------------------------------------------------------------------
// ws layout (64.5 MB): cos|sin (512K) | Qw 16M | Kw 16M | Vt 16M | X 16M
//   X: bf16(hs), then attention output.
//   Qw: Q during qkv+attn; then reused as bf16(Wo) scratch for out_gemm.
// d_out: bf16(Wqkv) scratch during qkv_gemm; overwritten by out_gemm.
// ---------------------------------------------------------------------------
extern "C" void kernel_launch(void* const* d_in, const int* in_sizes, int n_in,
                              void* d_out, int out_size, void* d_ws, size_t ws_size,
                              hipStream_t stream) {
    const float* hs = (const float*)d_in[0];
    const float* Wqkv = (const float*)d_in[1];
    const float* bqkv = (const float*)d_in[2];
    const float* Wo = (const float*)d_in[3];
    const float* bo = (const float*)d_in[4];
    float* out = (float*)d_out;

    char* ws = (char*)d_ws;
    float* cost = (float*)ws;
    float* sint = cost + NS * 32;
    bf16* Qw = (bf16*)(ws + 524288);
    bf16* Kw = Qw + (size_t)NB * NH * NS * NHD;
    bf16* Vt = Kw + (size_t)NB * NH * NS * NHD;
    bf16* X = Vt + (size_t)NB * NH * NS * NHD;
    bf16* Wqkv_b = (bf16*)d_out;   // scratch inside d_out, dead before out_gemm
    bf16* Wo_b = Qw;               // Qw region is dead after attn

    rope_table_kernel<<<dim3(NS * 32 / 256), dim3(256), 0, stream>>>(cost, sint);
    cvt_bf16_kernel<<<dim3(NM * ND / 4 / 256), dim3(256), 0, stream>>>(
        (const float4*)hs, (bf16x4*)X);
    cvt_bf16_kernel<<<dim3(3 * ND * ND / 4 / 256), dim3(256), 0, stream>>>(
        (const float4*)Wqkv, (bf16x4*)Wqkv_b);
    qkv_rope_gemm<<<dim3(3 * ND / 128, NM / 128), dim3(256), 0, stream>>>(
        X, Wqkv_b, bqkv, cost, sint, Qw, Kw, Vt);
    attn_kernel<<<dim3(NS / 256, NB * NH), dim3(256), 0, stream>>>(Qw, Kw, Vt, X);
    cvt_bf16_kernel<<<dim3(ND * ND / 4 / 256), dim3(256), 0, stream>>>(
        (const float4*)Wo, (bf16x4*)Wo_b);
    out_gemm<<<dim3(ND / 128, NM / 128), dim3(256), 0, stream>>>(X, Wo_b, bo, out);
}

// Round 7
// 291.287 us; speedup vs baseline: 1.0722x; 1.0722x over previous
//
#include <hip/hip_runtime.h>
#include <hip/hip_bf16.h>
#include <cstdint>
#include <cstddef>

typedef __bf16 bf16;
typedef __bf16 bf16x4 __attribute__((ext_vector_type(4)));
typedef __bf16 bf16x8 __attribute__((ext_vector_type(8)));
typedef float f32x4 __attribute__((ext_vector_type(4)));

#define NB 4
#define NS 2048
#define ND 1024
#define NH 16
#define NHD 64
#define NM (NB * NS)  // 8192

// async global->LDS, 16B per lane; LDS dest = wave-uniform base + lane*16
__device__ inline void lds_dma16(const bf16* g, bf16* l) {
    __builtin_amdgcn_global_load_lds(
        (const __attribute__((address_space(1))) void*)g,
        (__attribute__((address_space(3))) void*)l, 16, 0, 0);
}

// ---------------------------------------------------------------------------
// RoPE cos/sin table: [s][f], f in [0,32), angle = s * 10000^(-f/32), fp32.
// ---------------------------------------------------------------------------
__global__ void rope_table_kernel(float* __restrict__ cost, float* __restrict__ sint) {
    int i = blockIdx.x * 256 + threadIdx.x;  // 0..65535
    int s = i >> 5, f = i & 31;
    float inv = exp2f(-(float)f * (13.287712379549449f / 32.0f));
    float ang = (float)s * inv;
    cost[i] = cosf(ang);
    sint[i] = sinf(ang);
}

// fp32 -> bf16 bulk convert (float4 per thread)
__global__ void cvt_bf16_kernel(const float4* __restrict__ in, bf16x4* __restrict__ out) {
    int i = blockIdx.x * 256 + threadIdx.x;
    float4 v = in[i];
    bf16x4 r = {(bf16)v.x, (bf16)v.y, (bf16)v.z, (bf16)v.w};
    out[i] = r;
}

// ---------------------------------------------------------------------------
// QKV GEMM: r5 single-buffer m97 structure (measured best). Fused RoPE.
// V epilogue: bf16x4 packed stores (r contiguous in Vt's s-dim) -> 16x fewer
// L2 line transactions than scalar.
// ---------------------------------------------------------------------------
__global__ void __launch_bounds__(256) qkv_rope_gemm(
    const bf16* __restrict__ A, const bf16* __restrict__ W,
    const float* __restrict__ bias,
    const float* __restrict__ cost, const float* __restrict__ sint,
    bf16* __restrict__ Qw, bf16* __restrict__ Kw, bf16* __restrict__ Vt) {
    __shared__ __attribute__((aligned(16))) bf16 lA[128 * 32];
    __shared__ __attribute__((aligned(16))) bf16 lB[128 * 32];

    int t = threadIdx.x, lane = t & 63, w = t >> 6;
    int col = lane & 15, quad = lane >> 4;
    int m0 = blockIdx.y * 128, n0 = blockIdx.x * 128;
    int wm = (w >> 1) * 64, wn = (w & 1) * 64;

    f32x4 acc[4][4];
#pragma unroll
    for (int i = 0; i < 4; ++i)
#pragma unroll
        for (int j = 0; j < 4; ++j) acc[i][j] = (f32x4){0.f, 0.f, 0.f, 0.f};

    const bf16* gA0 = A + (size_t)(m0 + w * 32 + (lane >> 2)) * ND + (lane & 3) * 8;
    const bf16* gA1 = gA0 + (size_t)16 * ND;
    const bf16* gB0 = W + (size_t)(n0 + w * 32 + (lane >> 2)) * ND + (lane & 3) * 8;
    const bf16* gB1 = gB0 + (size_t)16 * ND;
    bf16* ldsA0 = &lA[(w * 32) * 32];
    bf16* ldsA1 = &lA[(w * 32 + 16) * 32];
    bf16* ldsB0 = &lB[(w * 32) * 32];
    bf16* ldsB1 = &lB[(w * 32 + 16) * 32];

    for (int kt = 0; kt < ND; kt += 32) {
        lds_dma16(gA0 + kt, ldsA0);
        lds_dma16(gA1 + kt, ldsA1);
        lds_dma16(gB0 + kt, ldsB0);
        lds_dma16(gB1 + kt, ldsB1);
        __syncthreads();
        bf16x8 af[4], bg[4];
#pragma unroll
        for (int i = 0; i < 4; ++i)
            af[i] = *(const bf16x8*)&lA[(wm + i * 16 + col) * 32 + quad * 8];
#pragma unroll
        for (int j = 0; j < 4; ++j)
            bg[j] = *(const bf16x8*)&lB[(wn + j * 16 + col) * 32 + quad * 8];
#pragma unroll
        for (int i = 0; i < 4; ++i)
#pragma unroll
            for (int j = 0; j < 4; ++j)
                acc[i][j] = __builtin_amdgcn_mfma_f32_16x16x32_bf16(af[i], bg[j], acc[i][j], 0, 0, 0);
        __syncthreads();
    }

    // Epilogue. Wave's 64 n-cols lie in one (which, head) segment.
    int nseg = n0 + wn;
    int which = nseg >> 10;
    int h = (nseg >> 6) & (NH - 1);
    float bj[4];
#pragma unroll
    for (int j = 0; j < 4; ++j) bj[j] = bias[nseg + j * 16 + col];

    if (which == 2) {
        // V: packed bf16x4 along s (r-dim is contiguous in Vt[hd][s]).
        int mbase = m0 + wm;            // 64-aligned; never crosses a b-boundary
        int b = mbase >> 11;
        bf16* dsth = Vt + (size_t)(b * NH + h) * NHD * NS;
#pragma unroll
        for (int i = 0; i < 4; ++i) {
            int s = ((mbase + i * 16) & (NS - 1)) + quad * 4;
#pragma unroll
            for (int j = 0; j < 4; ++j) {
                bf16x4 pv = {(bf16)(acc[i][j][0] + bj[j]), (bf16)(acc[i][j][1] + bj[j]),
                             (bf16)(acc[i][j][2] + bj[j]), (bf16)(acc[i][j][3] + bj[j])};
                *(bf16x4*)(dsth + (size_t)(j * 16 + col) * NS + s) = pv;
            }
        }
    } else {
#pragma unroll
        for (int i = 0; i < 4; ++i) {
#pragma unroll
            for (int r = 0; r < 4; ++r) {
                int m = m0 + wm + i * 16 + quad * 4 + r;
                int b = m >> 11, s = m & (NS - 1);
                float v0 = acc[i][0][r] + bj[0];
                float v1 = acc[i][1][r] + bj[1];
                float v2 = acc[i][2][r] + bj[2];
                float v3 = acc[i][3][r] + bj[3];
                bf16* dst = (which ? Kw : Qw) + ((size_t)(b * NH + h) * NS + s) * NHD;
                float c0 = cost[s * 32 + col], s0 = sint[s * 32 + col];
                float c1 = cost[s * 32 + 16 + col], s1 = sint[s * 32 + 16 + col];
                dst[col] = (bf16)(v0 * c0 - v2 * s0);
                dst[16 + col] = (bf16)(v1 * c1 - v3 * s1);
                dst[32 + col] = (bf16)(v0 * s0 + v2 * c0);
                dst[48 + col] = (bf16)(v1 * s1 + v3 * c1);
            }
        }
    }
}

// ---------------------------------------------------------------------------
// Flash attention v6 (kept from r6): 64 q-rows/wave, 32-key tiles, dbuf LDS
// with one barrier/tile, in-lane P-fragment, fixed-max softmax.
// ---------------------------------------------------------------------------
__global__ void __launch_bounds__(256, 2) attn_kernel(
    const bf16* __restrict__ Qw, const bf16* __restrict__ Kw,
    const bf16* __restrict__ Vt, bf16* __restrict__ X) {
    const int LDK = 72;
    const int LV = 40;
    __shared__ __attribute__((aligned(16))) bf16 lK[2][32 * LDK];
    __shared__ __attribute__((aligned(16))) bf16 lV[2][64 * LV];

    int t = threadIdx.x, lane = t & 63, w = t >> 6;
    int col = lane & 15, q = lane >> 4;
    int bh = blockIdx.y, b = bh >> 4, h = bh & 15;
    int q0 = blockIdx.x * 256 + w * 64;
    const bf16* Qh = Qw + (size_t)bh * NS * NHD;
    const bf16* Kh = Kw + (size_t)bh * NS * NHD;
    const bf16* Vh = Vt + (size_t)bh * NHD * NS;

    int krow = t >> 3, kc = t & 7;
    int vrow = t >> 2, vc = t & 3;
    const bf16* gK = Kh + (size_t)krow * NHD + kc * 8;
    const bf16* gV = Vh + (size_t)vrow * NS + vc * 8;
    int wKoff = krow * LDK + kc * 8;
    int wVoff = vrow * LV + vc * 8;

    bf16x8 bQ[4][2];
#pragma unroll
    for (int mb = 0; mb < 4; ++mb)
#pragma unroll
        for (int h2 = 0; h2 < 2; ++h2)
            bQ[mb][h2] = *(const bf16x8*)(Qh + (size_t)(q0 + mb * 16 + col) * NHD + h2 * 32 + q * 8);

    f32x4 o[4][4];
#pragma unroll
    for (int mb = 0; mb < 4; ++mb)
#pragma unroll
        for (int hb = 0; hb < 4; ++hb) o[mb][hb] = (f32x4){0.f, 0.f, 0.f, 0.f};
    float dsum[4] = {0.f, 0.f, 0.f, 0.f};

    bf16x8 kr[2], vr[2];
    kr[0] = *(const bf16x8*)gK;
    vr[0] = *(const bf16x8*)gV;
    kr[1] = *(const bf16x8*)(gK + (size_t)32 * NHD);
    vr[1] = *(const bf16x8*)(gV + 32);
    *(bf16x8*)&lK[0][wKoff] = kr[0];
    *(bf16x8*)&lV[0][wVoff] = vr[0];

#pragma unroll 2
    for (int it = 0; it < 64; ++it) {
        __syncthreads();
        int cur = it & 1, nxt = cur ^ 1;
        if (it + 2 < 64) {
            kr[cur] = *(const bf16x8*)(gK + (size_t)(it + 2) * 32 * NHD);
            vr[cur] = *(const bf16x8*)(gV + (it + 2) * 32);
        }

        bf16x8 aK[2][2];
#pragma unroll
        for (int tb = 0; tb < 2; ++tb)
#pragma unroll
            for (int h2 = 0; h2 < 2; ++h2)
                aK[tb][h2] = *(const bf16x8*)&lK[cur][(tb * 16 + col) * LDK + h2 * 32 + q * 8];
        bf16x8 vf[4];
#pragma unroll
        for (int hb = 0; hb < 4; ++hb) {
            const bf16* vp = &lV[cur][(hb * 16 + col) * LV + q * 4];
            bf16x4 lo = *(const bf16x4*)vp;
            bf16x4 hi = *(const bf16x4*)(vp + 16);
            vf[hb] = __builtin_shufflevector(lo, hi, 0, 1, 2, 3, 4, 5, 6, 7);
        }
#pragma unroll
        for (int mb = 0; mb < 4; ++mb) {
            f32x4 s0 = (f32x4){0.f, 0.f, 0.f, 0.f};
            f32x4 s1 = (f32x4){0.f, 0.f, 0.f, 0.f};
            s0 = __builtin_amdgcn_mfma_f32_16x16x32_bf16(aK[0][0], bQ[mb][0], s0, 0, 0, 0);
            s0 = __builtin_amdgcn_mfma_f32_16x16x32_bf16(aK[0][1], bQ[mb][1], s0, 0, 0, 0);
            s1 = __builtin_amdgcn_mfma_f32_16x16x32_bf16(aK[1][0], bQ[mb][0], s1, 0, 0, 0);
            s1 = __builtin_amdgcn_mfma_f32_16x16x32_bf16(aK[1][1], bQ[mb][1], s1, 0, 0, 0);
            bf16x8 pf;
            float ds = 0.f;
#pragma unroll
            for (int r = 0; r < 4; ++r) {
                float p0 = __expf(s0[r] * 0.125f);
                float p1 = __expf(s1[r] * 0.125f);
                pf[r] = (bf16)p0;
                pf[4 + r] = (bf16)p1;
                ds += p0 + p1;
            }
            dsum[mb] += ds;
#pragma unroll
            for (int hb = 0; hb < 4; ++hb)
                o[mb][hb] = __builtin_amdgcn_mfma_f32_16x16x32_bf16(vf[hb], pf, o[mb][hb], 0, 0, 0);
        }

        if (it + 1 < 64) {
            *(bf16x8*)&lK[nxt][wKoff] = kr[nxt];
            *(bf16x8*)&lV[nxt][wVoff] = vr[nxt];
        }
    }

#pragma unroll
    for (int mb = 0; mb < 4; ++mb) {
        dsum[mb] += __shfl_xor(dsum[mb], 16);
        dsum[mb] += __shfl_xor(dsum[mb], 32);
        float linv = 1.0f / dsum[mb];
        int s = q0 + mb * 16 + col;
        bf16* dst = X + (size_t)(b * NS + s) * ND + h * NHD;
#pragma unroll
        for (int hb = 0; hb < 4; ++hb) {
            bf16x4 ov = {(bf16)(o[mb][hb][0] * linv), (bf16)(o[mb][hb][1] * linv),
                         (bf16)(o[mb][hb][2] * linv), (bf16)(o[mb][hb][3] * linv)};
            *(bf16x4*)(dst + hb * 16 + q * 4) = ov;
        }
    }
}

// ---------------------------------------------------------------------------
// Output projection: r5 single-buffer structure (measured best). out fp32.
// ---------------------------------------------------------------------------
__global__ void __launch_bounds__(256) out_gemm(
    const bf16* __restrict__ A, const bf16* __restrict__ W,
    const float* __restrict__ bias, float* __restrict__ out) {
    __shared__ __attribute__((aligned(16))) bf16 lA[128 * 32];
    __shared__ __attribute__((aligned(16))) bf16 lB[128 * 32];

    int t = threadIdx.x, lane = t & 63, w = t >> 6;
    int col = lane & 15, quad = lane >> 4;
    int m0 = blockIdx.y * 128, n0 = blockIdx.x * 128;
    int wm = (w >> 1) * 64, wn = (w & 1) * 64;

    f32x4 acc[4][4];
#pragma unroll
    for (int i = 0; i < 4; ++i)
#pragma unroll
        for (int j = 0; j < 4; ++j) acc[i][j] = (f32x4){0.f, 0.f, 0.f, 0.f};

    const bf16* gA0 = A + (size_t)(m0 + w * 32 + (lane >> 2)) * ND + (lane & 3) * 8;
    const bf16* gA1 = gA0 + (size_t)16 * ND;
    const bf16* gB0 = W + (size_t)(n0 + w * 32 + (lane >> 2)) * ND + (lane & 3) * 8;
    const bf16* gB1 = gB0 + (size_t)16 * ND;
    bf16* ldsA0 = &lA[(w * 32) * 32];
    bf16* ldsA1 = &lA[(w * 32 + 16) * 32];
    bf16* ldsB0 = &lB[(w * 32) * 32];
    bf16* ldsB1 = &lB[(w * 32 + 16) * 32];

    for (int kt = 0; kt < ND; kt += 32) {
        lds_dma16(gA0 + kt, ldsA0);
        lds_dma16(gA1 + kt, ldsA1);
        lds_dma16(gB0 + kt, ldsB0);
        lds_dma16(gB1 + kt, ldsB1);
        __syncthreads();
        bf16x8 af[4], bg[4];
#pragma unroll
        for (int i = 0; i < 4; ++i)
            af[i] = *(const bf16x8*)&lA[(wm + i * 16 + col) * 32 + quad * 8];
#pragma unroll
        for (int j = 0; j < 4; ++j)
            bg[j] = *(const bf16x8*)&lB[(wn + j * 16 + col) * 32 + quad * 8];
#pragma unroll
        for (int i = 0; i < 4; ++i)
#pragma unroll
            for (int j = 0; j < 4; ++j)
                acc[i][j] = __builtin_amdgcn_mfma_f32_16x16x32_bf16(af[i], bg[j], acc[i][j], 0, 0, 0);
        __syncthreads();
    }

    float bj[4];
#pragma unroll
    for (int j = 0; j < 4; ++j) bj[j] = bias[n0 + wn + j * 16 + col];
#pragma unroll
    for (int i = 0; i < 4; ++i)
#pragma unroll
        for (int r = 0; r < 4; ++r) {
            int m = m0 + wm + i * 16 + quad * 4 + r;
#pragma unroll
            for (int j = 0; j < 4; ++j)
                out[(size_t)m * ND + n0 + wn + j * 16 + col] = acc[i][j][r] + bj[j];
        }
}

// ---------------------------------------------------------------------------
// ws layout (64.5 MB): cos|sin (512K) | Qw 16M | Kw 16M | Vt 16M | X 16M
//   X: bf16(hs), then attention output.
//   Qw: Q during qkv+attn; then reused as bf16(Wo) scratch for out_gemm.
// d_out: bf16(Wqkv) scratch during qkv_gemm; overwritten by out_gemm.
// ---------------------------------------------------------------------------
extern "C" void kernel_launch(void* const* d_in, const int* in_sizes, int n_in,
                              void* d_out, int out_size, void* d_ws, size_t ws_size,
                              hipStream_t stream) {
    const float* hs = (const float*)d_in[0];
    const float* Wqkv = (const float*)d_in[1];
    const float* bqkv = (const float*)d_in[2];
    const float* Wo = (const float*)d_in[3];
    const float* bo = (const float*)d_in[4];
    float* out = (float*)d_out;

    char* ws = (char*)d_ws;
    float* cost = (float*)ws;
    float* sint = cost + NS * 32;
    bf16* Qw = (bf16*)(ws + 524288);
    bf16* Kw = Qw + (size_t)NB * NH * NS * NHD;
    bf16* Vt = Kw + (size_t)NB * NH * NS * NHD;
    bf16* X = Vt + (size_t)NB * NH * NS * NHD;
    bf16* Wqkv_b = (bf16*)d_out;   // scratch inside d_out, dead before out_gemm
    bf16* Wo_b = Qw;               // Qw region is dead after attn

    rope_table_kernel<<<dim3(NS * 32 / 256), dim3(256), 0, stream>>>(cost, sint);
    cvt_bf16_kernel<<<dim3(NM * ND / 4 / 256), dim3(256), 0, stream>>>(
        (const float4*)hs, (bf16x4*)X);
    cvt_bf16_kernel<<<dim3(3 * ND * ND / 4 / 256), dim3(256), 0, stream>>>(
        (const float4*)Wqkv, (bf16x4*)Wqkv_b);
    qkv_rope_gemm<<<dim3(3 * ND / 128, NM / 128), dim3(256), 0, stream>>>(
        X, Wqkv_b, bqkv, cost, sint, Qw, Kw, Vt);
    attn_kernel<<<dim3(NS / 256, NB * NH), dim3(256), 0, stream>>>(Qw, Kw, Vt, X);
    cvt_bf16_kernel<<<dim3(ND * ND / 4 / 256), dim3(256), 0, stream>>>(
        (const float4*)Wo, (bf16x4*)Wo_b);
    out_gemm<<<dim3(ND / 128, NM / 128), dim3(256), 0, stream>>>(X, Wo_b, bo, out);
}